// Round 2
// baseline (643.023 us; speedup 1.0000x reference)
//
#include <hip/hip_runtime.h>

#define N_NODES 1000000
#define D_FEAT 128
#define BATCH 100000
#define NUM_SAMPLE 10

typedef float v4f __attribute__((ext_vector_type(4)));

// 32 threads per output row; each thread owns one float4 (4 feats).
// Row = 128 floats = 32 float4 = 512 B -> a half-wave reads one full row
// coalesced; two rows per wave64.
//
// Changes vs 641us baseline:
//  - __launch_bounds__(256, 8): force <=64 VGPR so occupancy is 8 waves/SIMD
//    (was ~75-85 VGPR -> 4 waves/SIMD; gfx950 occupancy steps at 64/128/256).
//  - 32-bit byte offsets: n<<9 + col<<4 < 2^31, so feat loads compile to
//    SGPR-base + 32-bit voffset (no v_mad_u64 per sample, fewer addr VGPRs).
//  - idx prologue as 5x int2 loads (40 B per row is 8-byte aligned) instead
//    of 10 scalar int loads: fewer vmem instrs, earlier issue.
//  - non-temporal store for out (via native clang vector type): 51 MB of
//    streaming writes stop evicting feature lines from L2/L3.
__global__ __launch_bounds__(256, 8) void mean_agg_kernel(
    const char* __restrict__ featb,    // features as bytes, [N_NODES * 512]
    const int2* __restrict__ idx2,     // [BATCH * 5] (pairs of int32 indices)
    float4* __restrict__ out)          // [BATCH * 32] float4
{
    const int gid = blockIdx.x * blockDim.x + threadIdx.x;
    const int row = gid >> 5;        // output row
    const int col = gid & 31;        // float4 column within row
    if (row >= BATCH) return;

    // Load all 10 indices with 5 x 8-byte loads (row*40 bytes is 8-aligned).
    const int2* ip = idx2 + row * 5;
    const int2 a0 = ip[0];
    const int2 a1 = ip[1];
    const int2 a2 = ip[2];
    const int2 a3 = ip[3];
    const int2 a4 = ip[4];

    int n[NUM_SAMPLE];
    n[0] = a0.x; n[1] = a0.y;
    n[2] = a1.x; n[3] = a1.y;
    n[4] = a2.x; n[5] = a2.y;
    n[6] = a3.x; n[7] = a3.y;
    n[8] = a4.x; n[9] = a4.y;

    const unsigned cb = (unsigned)(col << 4);   // byte offset of this float4

    float4 acc = make_float4(0.f, 0.f, 0.f, 0.f);
#pragma unroll
    for (int s = 0; s < NUM_SAMPLE; ++s) {
        // n < 1e6 -> n<<9 < 2^30; +cb stays well under 2^31: 32-bit offset.
        const unsigned off = ((unsigned)n[s] << 9) + cb;
        const float4 v = *(const float4*)(featb + off);
        acc.x += v.x;
        acc.y += v.y;
        acc.z += v.z;
        acc.w += v.w;
    }
    const float inv = 1.0f / (float)NUM_SAMPLE;
    acc.x *= inv; acc.y *= inv; acc.z *= inv; acc.w *= inv;

    v4f accv;
    accv.x = acc.x; accv.y = acc.y; accv.z = acc.z; accv.w = acc.w;
    __builtin_nontemporal_store(accv, (v4f*)&out[row * 32 + col]);
}

extern "C" void kernel_launch(void* const* d_in, const int* in_sizes, int n_in,
                              void* d_out, int out_size, void* d_ws, size_t ws_size,
                              hipStream_t stream) {
    const char* featb = (const char*)d_in[0];
    const int2* idx2 = (const int2*)d_in[1];
    float4* out = (float4*)d_out;

    const int total_threads = BATCH * 32;           // 3.2M
    const int block = 256;
    const int grid = (total_threads + block - 1) / block;  // 12500
    mean_agg_kernel<<<grid, block, 0, stream>>>(featb, idx2, out);
}

// Round 3
// 639.043 us; speedup vs baseline: 1.0062x; 1.0062x over previous
//
#include <hip/hip_runtime.h>

#define N_NODES 1000000
#define D_FEAT 128
#define BATCH 100000
#define NUM_SAMPLE 10

typedef float v4f __attribute__((ext_vector_type(4)));

// 32 threads per output row; each thread owns one float4 (4 feats).
// Row = 128 floats = 32 float4 = 512 B -> a half-wave reads one full row
// coalesced; two rows per wave64.
//
// R2 post-mortem: addressing/occupancy/idx/NT-store all neutral (637->643us).
// Model: random-gather is per-CU outstanding-miss-queue limited (~30 lines
// in flight/CU x ~650ns cold miss = ~1.8 TB/s effective). This round's single
// change: NON-TEMPORAL feature loads (bypass L1 allocation). Feature lines
// have zero L1 reuse (each line touched once per CU; repeats land on other
// CUs), so L1 only adds queue pressure. If the L1/TCP MSHR queue is the wall,
// nt loads routed at L2 should deepen in-flight capacity -> dur drops.
// idx loads stay normal (32 threads of a row share the same 40 B -> L1 hit).
__global__ __launch_bounds__(256, 8) void mean_agg_kernel(
    const char* __restrict__ featb,    // features as bytes, [N_NODES * 512]
    const int2* __restrict__ idx2,     // [BATCH * 5] (pairs of int32 indices)
    float4* __restrict__ out)          // [BATCH * 32] float4
{
    const int gid = blockIdx.x * blockDim.x + threadIdx.x;
    const int row = gid >> 5;        // output row
    const int col = gid & 31;        // float4 column within row
    if (row >= BATCH) return;

    // Load all 10 indices with 5 x 8-byte loads (row*40 bytes is 8-aligned).
    const int2* ip = idx2 + row * 5;
    const int2 a0 = ip[0];
    const int2 a1 = ip[1];
    const int2 a2 = ip[2];
    const int2 a3 = ip[3];
    const int2 a4 = ip[4];

    int n[NUM_SAMPLE];
    n[0] = a0.x; n[1] = a0.y;
    n[2] = a1.x; n[3] = a1.y;
    n[4] = a2.x; n[5] = a2.y;
    n[6] = a3.x; n[7] = a3.y;
    n[8] = a4.x; n[9] = a4.y;

    const unsigned cb = (unsigned)(col << 4);   // byte offset of this float4

    float acc_x = 0.f, acc_y = 0.f, acc_z = 0.f, acc_w = 0.f;
#pragma unroll
    for (int s = 0; s < NUM_SAMPLE; ++s) {
        // n < 1e6 -> n<<9 < 2^30; +cb stays well under 2^31: 32-bit offset.
        const unsigned off = ((unsigned)n[s] << 9) + cb;
        const v4f v = __builtin_nontemporal_load((const v4f*)(featb + off));
        acc_x += v.x;
        acc_y += v.y;
        acc_z += v.z;
        acc_w += v.w;
    }
    const float inv = 1.0f / (float)NUM_SAMPLE;
    v4f accv;
    accv.x = acc_x * inv;
    accv.y = acc_y * inv;
    accv.z = acc_z * inv;
    accv.w = acc_w * inv;

    __builtin_nontemporal_store(accv, (v4f*)&out[row * 32 + col]);
}

extern "C" void kernel_launch(void* const* d_in, const int* in_sizes, int n_in,
                              void* d_out, int out_size, void* d_ws, size_t ws_size,
                              hipStream_t stream) {
    const char* featb = (const char*)d_in[0];
    const int2* idx2 = (const int2*)d_in[1];
    float4* out = (float4*)d_out;

    const int total_threads = BATCH * 32;           // 3.2M
    const int block = 256;
    const int grid = (total_threads + block - 1) / block;  // 12500
    mean_agg_kernel<<<grid, block, 0, stream>>>(featb, idx2, out);
}